// Round 5
// baseline (117.619 us; speedup 1.0000x reference)
//
#include <hip/hip_runtime.h>

#define NN 50000
#define NE 600000
#define DI 128
#define DH 16
#define DC 8
#define NBLK 196   // ceil(NN/256)

// ---------------- layer-1 GEMM: xl = x @ W1l, xr = x @ W1r (+ zero deg) ----------------
__global__ __launch_bounds__(256) void k_gemm1(
    const float* __restrict__ x,
    const float* __restrict__ W1l,
    const float* __restrict__ W1r,
    float* __restrict__ xl,
    float* __restrict__ xr,
    int* __restrict__ deg)
{
    int n = blockIdx.x * 256 + threadIdx.x;
    if (n < NN) deg[n] = 0;                 // fused zero-init

    __shared__ float Wc[DI][32];   // [k][j]: j<16 -> W1l, j>=16 -> W1r
    for (int i = threadIdx.x; i < DI * DH; i += 256) {
        int k = i >> 4, j = i & 15;
        Wc[k][j]      = W1l[i];
        Wc[k][j + 16] = W1r[i];
    }
    __syncthreads();
    if (n >= NN) return;

    float acc[32];
#pragma unroll
    for (int j = 0; j < 32; ++j) acc[j] = 0.f;

    const float4* xrow = (const float4*)(x + (size_t)n * DI);
#pragma unroll 2
    for (int k4 = 0; k4 < DI / 4; ++k4) {
        float4 xv = xrow[k4];
        float xa[4] = {xv.x, xv.y, xv.z, xv.w};
#pragma unroll
        for (int kk = 0; kk < 4; ++kk) {
            const float4* wr = (const float4*)(Wc[k4 * 4 + kk]);
#pragma unroll
            for (int j4 = 0; j4 < 8; ++j4) {
                float4 w = wr[j4];
                acc[j4 * 4 + 0] += xa[kk] * w.x;
                acc[j4 * 4 + 1] += xa[kk] * w.y;
                acc[j4 * 4 + 2] += xa[kk] * w.z;
                acc[j4 * 4 + 3] += xa[kk] * w.w;
            }
        }
    }
    float4* o1 = (float4*)(xl + (size_t)n * DH);
    float4* o2 = (float4*)(xr + (size_t)n * DH);
#pragma unroll
    for (int q = 0; q < 4; ++q) {
        o1[q] = make_float4(acc[q*4+0], acc[q*4+1], acc[q*4+2], acc[q*4+3]);
        o2[q] = make_float4(acc[16+q*4+0], acc[16+q*4+1], acc[16+q*4+2], acc[16+q*4+3]);
    }
}

// ---------------- degree histogram ----------------
__global__ __launch_bounds__(256) void k_hist(const int* __restrict__ dst, int* __restrict__ deg)
{
    int e = blockIdx.x * 256 + threadIdx.x;
    if (e < NE) atomicAdd(&deg[dst[e]], 1);
}

// ---------------- scan phase A: per-block sums ----------------
__global__ __launch_bounds__(256) void k_blocksum(const int* __restrict__ deg, int* __restrict__ bs)
{
    int i = blockIdx.x * 256 + threadIdx.x;
    int v = (i < NN) ? deg[i] : 0;
#pragma unroll
    for (int off = 32; off; off >>= 1) v += __shfl_xor(v, off, 64);
    __shared__ int ws[4];
    int w = threadIdx.x >> 6, lane = threadIdx.x & 63;
    if (lane == 0) ws[w] = v;
    __syncthreads();
    if (threadIdx.x == 0) bs[blockIdx.x] = ws[0] + ws[1] + ws[2] + ws[3];
}

// ---------------- scan phase B: exclusive scan of NBLK block sums (1 block) ----------------
__global__ __launch_bounds__(256) void k_scanblk(const int* __restrict__ bs, int* __restrict__ boff)
{
    int tid = threadIdx.x, w = tid >> 6, lane = tid & 63;
    int v = (tid < NBLK) ? bs[tid] : 0;
    int s = v;
#pragma unroll
    for (int off = 1; off < 64; off <<= 1) {
        int t = __shfl_up(s, off, 64);
        if (lane >= off) s += t;
    }
    __shared__ int wsum[4];
    if (lane == 63) wsum[w] = s;
    __syncthreads();
    int woff = 0;
    for (int k = 0; k < w; ++k) woff += wsum[k];
    if (tid < NBLK) boff[tid] = woff + s - v;   // exclusive
}

// ---------------- scan phase C: per-block rescan + offset; writes rowstart & cursor ----------------
__global__ __launch_bounds__(256) void k_scanfinal(
    const int* __restrict__ deg, const int* __restrict__ boff,
    int* __restrict__ rowstart, int* __restrict__ cursor)
{
    int i = blockIdx.x * 256 + threadIdx.x;
    int w = threadIdx.x >> 6, lane = threadIdx.x & 63;
    int v = (i < NN) ? deg[i] : 0;
    int s = v;
#pragma unroll
    for (int off = 1; off < 64; off <<= 1) {
        int t = __shfl_up(s, off, 64);
        if (lane >= off) s += t;
    }
    __shared__ int wsum[4];
    if (lane == 63) wsum[w] = s;
    __syncthreads();
    int woff = 0;
    for (int k = 0; k < w; ++k) woff += wsum[k];
    int ex = boff[blockIdx.x] + woff + s - v;
    if (i < NN) { rowstart[i] = ex; cursor[i] = ex; }
    if (i == 0) rowstart[NN] = NE;
}

// ---------------- CSR fill: csr[cursor[d]++] = src ----------------
__global__ __launch_bounds__(256) void k_fill(
    const int* __restrict__ src, const int* __restrict__ dst,
    int* __restrict__ cursor, int* __restrict__ csr)
{
    int e = blockIdx.x * 256 + threadIdx.x;
    if (e >= NE) return;
    int pos = atomicAdd(&cursor[dst[e]], 1);
    csr[pos] = src[e];
}

// ---------------- agg1 (4-way row split): P1[s][n][16] = partial sum of xl over chunk s ----------------
__global__ __launch_bounds__(256) void k_agg1(
    const int* __restrict__ rowstart, const int* __restrict__ csr,
    const float* __restrict__ xl, float* __restrict__ P1)
{
    int t = blockIdx.x * 256 + threadIdx.x;
    if (t >= NN * 16) return;
    int n = t >> 4, s = (t >> 2) & 3, q = t & 3;
    int beg = rowstart[n], end = rowstart[n + 1];
    int len = end - beg;
    int chunk = (len + 3) >> 2;
    int c0 = beg + s * chunk;
    int c1 = min(c0 + chunk, end);
    float4 a0 = make_float4(0.f, 0.f, 0.f, 0.f);
    float4 a1 = make_float4(0.f, 0.f, 0.f, 0.f);
    int j = c0;
    for (; j + 1 < c1; j += 2) {
        int e0 = csr[j], e1 = csr[j + 1];
        float4 v0 = *(const float4*)(xl + e0 * DH + q * 4);
        float4 v1 = *(const float4*)(xl + e1 * DH + q * 4);
        a0.x += v0.x; a0.y += v0.y; a0.z += v0.z; a0.w += v0.w;
        a1.x += v1.x; a1.y += v1.y; a1.z += v1.z; a1.w += v1.w;
    }
    if (j < c1) {
        int e0 = csr[j];
        float4 v0 = *(const float4*)(xl + e0 * DH + q * 4);
        a0.x += v0.x; a0.y += v0.y; a0.z += v0.z; a0.w += v0.w;
    }
    float4 o = make_float4(a0.x + a1.x, a0.y + a1.y, a0.z + a1.z, a0.w + a1.w);
    *(float4*)(P1 + (size_t)s * NN * DH + (size_t)n * DH + q * 4) = o;
}

// ---------------- combine P1 -> h = relu(mean + b1 + xr), fused layer-2 GEMM -> zl, zr ----------------
__global__ __launch_bounds__(256) void k_hcomb(
    const float* __restrict__ P1, const int* __restrict__ rowstart,
    const float* __restrict__ xr, const float* __restrict__ b1,
    const float* __restrict__ W2l, const float* __restrict__ W2r,
    float* __restrict__ zl, float* __restrict__ zr)
{
    __shared__ float W2[DH][16];   // [k][j]: j<8 -> W2l, j>=8 -> W2r
    __shared__ float b1s[DH];
    if (threadIdx.x < DH * DC) {
        int k = threadIdx.x >> 3, j = threadIdx.x & 7;
        W2[k][j]     = W2l[threadIdx.x];
        W2[k][j + 8] = W2r[threadIdx.x];
    }
    if (threadIdx.x < DH) b1s[threadIdx.x] = b1[threadIdx.x];
    __syncthreads();

    int n = blockIdx.x * 256 + threadIdx.x;
    if (n >= NN) return;

    int beg = rowstart[n], end = rowstart[n + 1];
    float inv = 1.0f / fmaxf((float)(end - beg), 1.0f);

    float4 sum[4];
#pragma unroll
    for (int q = 0; q < 4; ++q) sum[q] = make_float4(0.f, 0.f, 0.f, 0.f);
#pragma unroll
    for (int s = 0; s < 4; ++s) {
        const float4* pp = (const float4*)(P1 + (size_t)s * NN * DH + (size_t)n * DH);
#pragma unroll
        for (int q = 0; q < 4; ++q) {
            float4 v = pp[q];
            sum[q].x += v.x; sum[q].y += v.y; sum[q].z += v.z; sum[q].w += v.w;
        }
    }
    const float4* rp = (const float4*)(xr + (size_t)n * DH);
    float hv[DH];
#pragma unroll
    for (int q = 0; q < 4; ++q) {
        float4 r = rp[q];
        hv[q*4+0] = fmaxf(sum[q].x * inv + b1s[q*4+0] + r.x, 0.f);
        hv[q*4+1] = fmaxf(sum[q].y * inv + b1s[q*4+1] + r.y, 0.f);
        hv[q*4+2] = fmaxf(sum[q].z * inv + b1s[q*4+2] + r.z, 0.f);
        hv[q*4+3] = fmaxf(sum[q].w * inv + b1s[q*4+3] + r.w, 0.f);
    }

    float acc[16];
#pragma unroll
    for (int jj = 0; jj < 16; ++jj) acc[jj] = 0.f;
#pragma unroll
    for (int k = 0; k < DH; ++k) {
        const float4* wr = (const float4*)(W2[k]);
        float hs = hv[k];
#pragma unroll
        for (int j4 = 0; j4 < 4; ++j4) {
            float4 w = wr[j4];
            acc[j4*4+0] += hs * w.x;
            acc[j4*4+1] += hs * w.y;
            acc[j4*4+2] += hs * w.z;
            acc[j4*4+3] += hs * w.w;
        }
    }
    float4* zlo = (float4*)(zl + (size_t)n * DC);
    float4* zro = (float4*)(zr + (size_t)n * DC);
    zlo[0] = make_float4(acc[0], acc[1], acc[2], acc[3]);
    zlo[1] = make_float4(acc[4], acc[5], acc[6], acc[7]);
    zro[0] = make_float4(acc[8], acc[9], acc[10], acc[11]);
    zro[1] = make_float4(acc[12], acc[13], acc[14], acc[15]);
}

// ---------------- agg2 (4-way row split): P2[s][n][8] = partial sum of zl over chunk s ----------------
__global__ __launch_bounds__(256) void k_agg2(
    const int* __restrict__ rowstart, const int* __restrict__ csr,
    const float* __restrict__ zl, float* __restrict__ P2)
{
    int t = blockIdx.x * 256 + threadIdx.x;
    if (t >= NN * 8) return;
    int n = t >> 3, s = (t >> 1) & 3, q = t & 1;
    int beg = rowstart[n], end = rowstart[n + 1];
    int len = end - beg;
    int chunk = (len + 3) >> 2;
    int c0 = beg + s * chunk;
    int c1 = min(c0 + chunk, end);
    float4 a0 = make_float4(0.f, 0.f, 0.f, 0.f);
    float4 a1 = make_float4(0.f, 0.f, 0.f, 0.f);
    int j = c0;
    for (; j + 1 < c1; j += 2) {
        int e0 = csr[j], e1 = csr[j + 1];
        float4 v0 = *(const float4*)(zl + e0 * DC + q * 4);
        float4 v1 = *(const float4*)(zl + e1 * DC + q * 4);
        a0.x += v0.x; a0.y += v0.y; a0.z += v0.z; a0.w += v0.w;
        a1.x += v1.x; a1.y += v1.y; a1.z += v1.z; a1.w += v1.w;
    }
    if (j < c1) {
        int e0 = csr[j];
        float4 v0 = *(const float4*)(zl + e0 * DC + q * 4);
        a0.x += v0.x; a0.y += v0.y; a0.z += v0.z; a0.w += v0.w;
    }
    float4 o = make_float4(a0.x + a1.x, a0.y + a1.y, a0.z + a1.z, a0.w + a1.w);
    *(float4*)(P2 + (size_t)s * NN * DC + (size_t)n * DC + q * 4) = o;
}

// ---------------- combine P2 -> out = mean + b2 + zr ----------------
__global__ __launch_bounds__(256) void k_out(
    const float* __restrict__ P2, const int* __restrict__ rowstart,
    const float* __restrict__ zr, const float* __restrict__ b2,
    float* __restrict__ out)
{
    int t = blockIdx.x * 256 + threadIdx.x;
    if (t >= NN * 2) return;
    int n = t >> 1, q = t & 1;
    int beg = rowstart[n], end = rowstart[n + 1];
    float inv = 1.0f / fmaxf((float)(end - beg), 1.0f);
    float4 sum = make_float4(0.f, 0.f, 0.f, 0.f);
#pragma unroll
    for (int s = 0; s < 4; ++s) {
        float4 v = *(const float4*)(P2 + (size_t)s * NN * DC + (size_t)n * DC + q * 4);
        sum.x += v.x; sum.y += v.y; sum.z += v.z; sum.w += v.w;
    }
    float4 r  = *(const float4*)(zr + t * 4);   // t*4 == n*8 + q*4
    float4 bb = *(const float4*)(b2 + q * 4);
    float4 o;
    o.x = sum.x * inv + bb.x + r.x;
    o.y = sum.y * inv + bb.y + r.y;
    o.z = sum.z * inv + bb.z + r.z;
    o.w = sum.w * inv + bb.w + r.w;
    *(float4*)(out + t * 4) = o;
}

extern "C" void kernel_launch(void* const* d_in, const int* in_sizes, int n_in,
                              void* d_out, int out_size, void* d_ws, size_t ws_size,
                              hipStream_t stream)
{
    const float* x   = (const float*)d_in[0];
    const int*   ei  = (const int*)d_in[1];
    const float* W1l = (const float*)d_in[2];
    const float* b1  = (const float*)d_in[3];
    const float* W1r = (const float*)d_in[4];
    const float* W2l = (const float*)d_in[5];
    const float* b2  = (const float*)d_in[6];
    const float* W2r = (const float*)d_in[7];
    float* out = (float*)d_out;

    const int* src = ei;
    const int* dst = ei + NE;

    // ---- workspace layout (floats first, 16B-aligned) ----
    float* xl = (float*)d_ws;                  // NN*16
    float* xr = xl + (size_t)NN * DH;          // NN*16
    float* P1 = xr + (size_t)NN * DH;          // 4*NN*16
    float* zl = P1 + (size_t)4 * NN * DH;      // NN*8
    float* zr = zl + (size_t)NN * DC;          // NN*8
    float* P2 = zr + (size_t)NN * DC;          // 4*NN*8
    int* deg      = (int*)(P2 + (size_t)4 * NN * DC);  // NN
    int* cursor   = deg + NN;                  // NN
    int* rowstart = cursor + NN;               // NN+1
    int* csr      = rowstart + NN + 1;         // NE
    int* bs       = csr + NE;                  // NBLK
    int* boff     = bs + NBLK;                 // NBLK
    // total ~32 MB

    k_gemm1    <<<NBLK, 256, 0, stream>>>(x, W1l, W1r, xl, xr, deg);
    k_hist     <<<(NE + 255) / 256, 256, 0, stream>>>(dst, deg);
    k_blocksum <<<NBLK, 256, 0, stream>>>(deg, bs);
    k_scanblk  <<<1, 256, 0, stream>>>(bs, boff);
    k_scanfinal<<<NBLK, 256, 0, stream>>>(deg, boff, rowstart, cursor);
    k_fill     <<<(NE + 255) / 256, 256, 0, stream>>>(src, dst, cursor, csr);
    k_agg1     <<<(NN * 16 + 255) / 256, 256, 0, stream>>>(rowstart, csr, xl, P1);
    k_hcomb    <<<NBLK, 256, 0, stream>>>(P1, rowstart, xr, b1, W2l, W2r, zl, zr);
    k_agg2     <<<(NN * 8 + 255) / 256, 256, 0, stream>>>(rowstart, csr, zl, P2);
    k_out      <<<(NN * 2 + 255) / 256, 256, 0, stream>>>(P2, rowstart, zr, b2, out);
}